// Round 1
// baseline (498.628 us; speedup 1.0000x reference)
//
#include <hip/hip_runtime.h>

namespace {

constexpr int kB   = 512;
constexpr int kM   = 4096;
constexpr int kN   = 64;
constexpr int kK   = 64;
constexpr int kH   = 8;
constexpr int kDK  = 32;
constexpr float kEps = 1e-5f;
constexpr int NT   = 256;

__device__ __forceinline__ void ld4(const float* p, float r[4]) {
  float4 v = *reinterpret_cast<const float4*>(p);
  r[0] = v.x; r[1] = v.y; r[2] = v.z; r[3] = v.w;
}

__global__ __launch_bounds__(NT) void fused_attn_kernel(
    const float* __restrict__ features,
    const int*   __restrict__ sidx,
    const float* __restrict__ gamma,
    const float* __restrict__ beta,
    const float* __restrict__ Wq,
    const float* __restrict__ Wk,
    const float* __restrict__ Wv1,
    const float* __restrict__ Wv2,
    const float* __restrict__ Wfc,
    float* __restrict__ out) {
  // LDS: 24576 floats = 96 KB -> 1 block/CU
  __shared__ __align__(16) float s_feat[kM];        // raw feature row (gather source)
  __shared__ __align__(16) float s_qin[kM];         // LayerNorm output
  __shared__ __align__(16) float s_kf[kM];          // per-head gathered kf; aliased as s_o later
  __shared__ __align__(16) float s_q[kN * kDK];     // [n][d]
  __shared__ __align__(16) float s_key[kDK * kN];   // [d][n]
  __shared__ __align__(16) float s_v[kN * kK];      // [n][p]
  __shared__ __align__(16) float s_attn[kN * kN];   // [qi][n]

  const int b    = blockIdx.x;
  const int t    = threadIdx.x;
  const int lane = t & 63;
  const int wave = t >> 6;   // 0..3

  const float* frow     = features + (size_t)b * kM;
  float*       out0     = out + (size_t)b * kM;
  float*       attn_out = out + (size_t)kB * kM + (size_t)b * (kH * kN * kN);

  float* s_red = s_v;  // reduction scratch overlay (s_v unwritten during LN)

  // ---------------- LayerNorm ----------------
  float xs[16];
  float sum = 0.f;
#pragma unroll
  for (int j = 0; j < 16; ++j) {
    int m = t + j * NT;
    float x = frow[m];
    xs[j] = x;
    s_feat[m] = x;
    sum += x;
  }
#pragma unroll
  for (int off = 32; off > 0; off >>= 1) sum += __shfl_xor(sum, off, 64);
  if (lane == 0) s_red[wave] = sum;
  __syncthreads();
  const float mu = (s_red[0] + s_red[1] + s_red[2] + s_red[3]) * (1.f / kM);
  float vs = 0.f;
#pragma unroll
  for (int j = 0; j < 16; ++j) { float d = xs[j] - mu; vs += d * d; }
#pragma unroll
  for (int off = 32; off > 0; off >>= 1) vs += __shfl_xor(vs, off, 64);
  __syncthreads();  // everyone done reading s_red[0..3]
  if (lane == 0) s_red[wave] = vs;
  __syncthreads();
  const float var  = (s_red[0] + s_red[1] + s_red[2] + s_red[3]) * (1.f / kM);
  const float rstd = rsqrtf(var + kEps);
#pragma unroll
  for (int j = 0; j < 16; ++j) {
    int m = t + j * NT;
    s_qin[m] = (xs[j] - mu) * rstd * gamma[m] + beta[m];
  }

  // fc accumulator lives in registers across heads: final[nf0+i][of0+j]
  float facc[4][4];
#pragma unroll
  for (int i = 0; i < 4; ++i)
#pragma unroll
    for (int j = 0; j < 4; ++j) facc[i][j] = 0.f;

  // tile mappings
  const int d0  = (t & 15) * 2;   // q/key: 2 d-rows
  const int n0  = (t >> 4) * 4;   // q/key: 4 n-rows
  const int qi0 = (t >> 4) * 4;   // scores/o: 4 query rows
  const int sn0 = (t & 15) * 4;   // scores/o: 4 cols
  const int nf0 = (t >> 4) * 4;   // fc: 4 n rows
  const int of0 = (t & 15) * 4;   // fc: 4 o cols
  const int vn  = t >> 2;         // v-conv: row
  const int vp0 = (t & 3) * 16;   // v-conv: 16 positions

  for (int h = 0; h < kH; ++h) {
    // small per-head conv weights (uniform -> scalar regs)
    float w1[4][3], w2r[4];
#pragma unroll
    for (int d = 0; d < 4; ++d) {
#pragma unroll
      for (int tt = 0; tt < 3; ++tt) w1[d][tt] = Wv1[(h * 4 + d) * 3 + tt];
      w2r[d] = Wv2[h * 4 + d];
    }
    const int* idxh = sidx + h * kM;

    __syncthreads();  // prev head's fc done reading s_o(=s_kf); LN writes visible

    // ---- gather kf[n][k] = feat[idx[h][n*64+k]] ----
#pragma unroll
    for (int j = 0; j < 16; ++j) {
      int i = t + j * NT;
      s_kf[i] = s_feat[idxh[i]];
    }

    // ---- q projection: q[n][d] = sum_k qin[n*64+k] * Wq[(h*32+d)*64+k] ----
    {
      float qa[2][4] = {};
      const float4* wq0  = reinterpret_cast<const float4*>(Wq + (size_t)(h * 32 + d0) * 64);
      const float4* wq1  = reinterpret_cast<const float4*>(Wq + (size_t)(h * 32 + d0 + 1) * 64);
      const float4* qin4 = reinterpret_cast<const float4*>(s_qin);
#pragma unroll
      for (int k4 = 0; k4 < 16; ++k4) {
        float4 wa = wq0[k4], wb = wq1[k4];
#pragma unroll
        for (int i = 0; i < 4; ++i) {
          float4 x = qin4[(n0 + i) * 16 + k4];
          qa[0][i] += x.x * wa.x + x.y * wa.y + x.z * wa.z + x.w * wa.w;
          qa[1][i] += x.x * wb.x + x.y * wb.y + x.z * wb.z + x.w * wb.w;
        }
      }
#pragma unroll
      for (int i = 0; i < 4; ++i) {
        s_q[(n0 + i) * 32 + d0]     = qa[0][i];
        s_q[(n0 + i) * 32 + d0 + 1] = qa[1][i];
      }
    }
    __syncthreads();  // s_kf ready

    // ---- key: key[d][n] = sum_k kf[n*64+k] * Wk[(h*32+d)*64+k] ----
    {
      float ka[2][4] = {};
      const float4* wk0 = reinterpret_cast<const float4*>(Wk + (size_t)(h * 32 + d0) * 64);
      const float4* wk1 = reinterpret_cast<const float4*>(Wk + (size_t)(h * 32 + d0 + 1) * 64);
      const float4* kf4 = reinterpret_cast<const float4*>(s_kf);
#pragma unroll
      for (int k4 = 0; k4 < 16; ++k4) {
        float4 wa = wk0[k4], wb = wk1[k4];
#pragma unroll
        for (int i = 0; i < 4; ++i) {
          float4 x = kf4[(n0 + i) * 16 + k4];
          ka[0][i] += x.x * wa.x + x.y * wa.y + x.z * wa.z + x.w * wa.w;
          ka[1][i] += x.x * wb.x + x.y * wb.y + x.z * wb.z + x.w * wb.w;
        }
      }
#pragma unroll
      for (int i = 0; i < 4; ++i) {
        s_key[d0 * 64 + n0 + i]       = ka[0][i];
        s_key[(d0 + 1) * 64 + n0 + i] = ka[1][i];
      }
    }

    // ---- v: windowed conv + relu + residual ----
    {
#pragma unroll
      for (int pp = 0; pp < 16; ++pp) {
        int p = vp0 + pp;
        float x0 = s_kf[vn * 64 + p];
        float x1 = (p + 1 < 64) ? s_kf[vn * 64 + p + 1] : 0.f;
        float x2 = (p + 2 < 64) ? s_kf[vn * 64 + p + 2] : 0.f;
        float acc = x0;
#pragma unroll
        for (int d = 0; d < 4; ++d) {
          float v1 = x0 * w1[d][0] + x1 * w1[d][1] + x2 * w1[d][2];
          acc += fmaxf(v1, 0.f) * w2r[d];
        }
        s_v[vn * 64 + p] = acc;
      }
    }
    __syncthreads();  // s_key, s_v ready

    // ---- scores[qi][n] = (1/64) * sum_d q[qi][d] * key[d][n] ----
    {
      float sc[4][4] = {};
#pragma unroll
      for (int d4 = 0; d4 < 8; ++d4) {
        float qv[4][4];
#pragma unroll
        for (int i = 0; i < 4; ++i) ld4(&s_q[(qi0 + i) * 32 + d4 * 4], qv[i]);
#pragma unroll
        for (int dd = 0; dd < 4; ++dd) {
          float kv[4];
          ld4(&s_key[(d4 * 4 + dd) * 64 + sn0], kv);
#pragma unroll
          for (int i = 0; i < 4; ++i)
#pragma unroll
            for (int j = 0; j < 4; ++j) sc[i][j] += qv[i][dd] * kv[j];
        }
      }
#pragma unroll
      for (int i = 0; i < 4; ++i) {
        float4 v4 = make_float4(sc[i][0] * 0.015625f, sc[i][1] * 0.015625f,
                                sc[i][2] * 0.015625f, sc[i][3] * 0.015625f);
        *reinterpret_cast<float4*>(&s_attn[(qi0 + i) * 64 + sn0]) = v4;
      }
    }
    __syncthreads();

    // ---- softmax over n (row-wise, one row per wave-iteration) + attn out ----
    {
#pragma unroll
      for (int r = 0; r < 16; ++r) {
        int row = wave * 16 + r;
        float x = s_attn[row * 64 + lane];
        float mx = x;
#pragma unroll
        for (int off = 32; off > 0; off >>= 1) mx = fmaxf(mx, __shfl_xor(mx, off, 64));
        float e = __expf(x - mx);
        float ss = e;
#pragma unroll
        for (int off = 32; off > 0; off >>= 1) ss += __shfl_xor(ss, off, 64);
        float a = e / ss;
        s_attn[row * 64 + lane] = a;
        attn_out[(size_t)h * 4096 + row * 64 + lane] = a;
      }
    }
    __syncthreads();

    // ---- o[qi][s] = sum_n attn[qi][n] * v[n][s]  (into s_o = s_kf) ----
    {
      float oa[4][4] = {};
#pragma unroll
      for (int n4 = 0; n4 < 16; ++n4) {
        float av[4][4];
#pragma unroll
        for (int i = 0; i < 4; ++i) ld4(&s_attn[(qi0 + i) * 64 + n4 * 4], av[i]);
#pragma unroll
        for (int nn = 0; nn < 4; ++nn) {
          float vv[4];
          ld4(&s_v[(n4 * 4 + nn) * 64 + sn0], vv);
#pragma unroll
          for (int i = 0; i < 4; ++i)
#pragma unroll
            for (int j = 0; j < 4; ++j) oa[i][j] += av[i][nn] * vv[j];
        }
      }
#pragma unroll
      for (int i = 0; i < 4; ++i) {
        float4 v4 = make_float4(oa[i][0], oa[i][1], oa[i][2], oa[i][3]);
        *reinterpret_cast<float4*>(&s_kf[(qi0 + i) * 64 + sn0]) = v4;  // s_o
      }
    }
    __syncthreads();

    // ---- fc accumulate: final[n][o] += sum_s o[n][s] * Wfc[o*512 + h*64 + s] ----
    {
#pragma unroll
      for (int s4 = 0; s4 < 16; ++s4) {
        float ov[4][4];
#pragma unroll
        for (int i = 0; i < 4; ++i) ld4(&s_kf[(nf0 + i) * 64 + s4 * 4], ov[i]);
        float wv[4][4];
#pragma unroll
        for (int j = 0; j < 4; ++j) ld4(&Wfc[(size_t)(of0 + j) * 512 + h * 64 + s4 * 4], wv[j]);
#pragma unroll
        for (int ss = 0; ss < 4; ++ss)
#pragma unroll
          for (int i = 0; i < 4; ++i)
#pragma unroll
            for (int j = 0; j < 4; ++j) facc[i][j] += ov[i][ss] * wv[j][ss];
      }
    }
  }

  // ---- write final output ----
#pragma unroll
  for (int i = 0; i < 4; ++i) {
    float4 v4 = make_float4(facc[i][0], facc[i][1], facc[i][2], facc[i][3]);
    *reinterpret_cast<float4*>(&out0[(nf0 + i) * 64 + of0]) = v4;
  }
}

}  // namespace

extern "C" void kernel_launch(void* const* d_in, const int* in_sizes, int n_in,
                              void* d_out, int out_size, void* d_ws, size_t ws_size,
                              hipStream_t stream) {
  (void)in_sizes; (void)n_in; (void)out_size; (void)d_ws; (void)ws_size;
  const float* features = (const float*)d_in[0];
  const int*   sidx     = (const int*)d_in[1];
  const float* gamma    = (const float*)d_in[2];
  const float* beta     = (const float*)d_in[3];
  const float* Wq       = (const float*)d_in[4];
  const float* Wk       = (const float*)d_in[5];
  const float* Wv1      = (const float*)d_in[6];
  const float* Wv2      = (const float*)d_in[7];
  const float* Wfc      = (const float*)d_in[8];
  float* out = (float*)d_out;

  hipLaunchKernelGGL(fused_attn_kernel, dim3(kB), dim3(NT), 0, stream,
                     features, sidx, gamma, beta, Wq, Wk, Wv1, Wv2, Wfc, out);
}

// Round 2
// 166.292 us; speedup vs baseline: 2.9985x; 2.9985x over previous
//
#include <hip/hip_runtime.h>

typedef __bf16 v8bf __attribute__((ext_vector_type(8)));
typedef __bf16 v4bf __attribute__((ext_vector_type(4)));
typedef float  v4f  __attribute__((ext_vector_type(4)));

namespace {

constexpr int kB = 512, kM = 4096, kH = 8;

// ws layout (bytes)
constexpr size_t WS_QIN = 0;                                   // 512*4096 bf16 = 4 MB
constexpr size_t WS_O   = (size_t)4 << 20;                     // 32768*512 bf16 = 32 MB
constexpr size_t WS_WQ  = WS_O + (size_t)32768 * 512 * 2;      // 16384 bf16
constexpr size_t WS_WK  = WS_WQ + 32768;                       // 16384 bf16
constexpr size_t WS_WFC = WS_WK + 32768;                       // 32768 bf16
// total = WS_WFC + 65536 = 37,879,808 B (~36.2 MB)

// ---------------- K0: weight casts (1/64 score scale folded into Wq) ----------------
__global__ __launch_bounds__(256) void k0_weights(
    const float* __restrict__ Wq, const float* __restrict__ Wk,
    const float* __restrict__ Wfc,
    __bf16* __restrict__ wq, __bf16* __restrict__ wk, __bf16* __restrict__ wfc) {
  int i = blockIdx.x * 256 + threadIdx.x;
  if (i < 16384)      wq[i]          = (__bf16)(Wq[i] * 0.015625f);
  else if (i < 32768) wk[i - 16384]  = (__bf16)Wk[i - 16384];
  else                wfc[i - 32768] = (__bf16)Wfc[i - 32768];
}

// ---------------- K1: LayerNorm -> bf16 qin ----------------
__global__ __launch_bounds__(256) void k1_ln(
    const float* __restrict__ feat, const float* __restrict__ gamma,
    const float* __restrict__ beta, __bf16* __restrict__ qin) {
  __shared__ float red[4];
  const int b = blockIdx.x, t = threadIdx.x, lane = t & 63, wv = t >> 6;
  const float* frow = feat + (size_t)b * kM;
  float xs[16];
  float s = 0.f;
#pragma unroll
  for (int j = 0; j < 16; ++j) { float x = frow[t + j * 256]; xs[j] = x; s += x; }
#pragma unroll
  for (int o = 32; o > 0; o >>= 1) s += __shfl_xor(s, o);
  if (lane == 0) red[wv] = s;
  __syncthreads();
  const float mu = (red[0] + red[1] + red[2] + red[3]) * (1.f / kM);
  float v = 0.f;
#pragma unroll
  for (int j = 0; j < 16; ++j) { float d = xs[j] - mu; v += d * d; }
#pragma unroll
  for (int o = 32; o > 0; o >>= 1) v += __shfl_xor(v, o);
  __syncthreads();
  if (lane == 0) red[wv] = v;
  __syncthreads();
  const float var  = (red[0] + red[1] + red[2] + red[3]) * (1.f / kM);
  const float rstd = rsqrtf(var + 1e-5f);
#pragma unroll
  for (int j = 0; j < 16; ++j) {
    int m = t + j * 256;
    qin[(size_t)b * kM + m] = (__bf16)((xs[j] - mu) * rstd * gamma[m] + beta[m]);
  }
}

// ---------------- K2: per-(b,h) attention core, MFMA 16x16x32 bf16 ----------------
// LDS tiles padded: stride 72 (bank shift 4 dwords/row) or 40 (20 dwords/row) -> 2-way only.
__global__ __launch_bounds__(256, 4) void k2_attn(
    const float* __restrict__ feat, const int* __restrict__ sidx,
    const __bf16* __restrict__ qin, const __bf16* __restrict__ wq,
    const __bf16* __restrict__ wk, const float* __restrict__ Wv1,
    const float* __restrict__ Wv2, __bf16* __restrict__ o_ws,
    float* __restrict__ out) {
  __shared__ __align__(16) __bf16 smem[18944];  // 37,888 B -> 4 blocks/CU
  __bf16* s_kf = smem;          // 64 x 72  (kf, gathered, bf16)
  __bf16* s_q  = smem + 4608;   // 64 x 40  (q [n][d])
  __bf16* s_K  = smem + 7168;   // 64 x 40  (K [n][d])
  __bf16* s_vT = smem + 9728;   // 64 x 72  (v^T [s][n])
  __bf16* s_sc = smem + 14336;  // 64 x 72  (scores -> attn, in place)

  const int h = blockIdx.x, b = blockIdx.y;
  const int t = threadIdx.x, w = t >> 6, lid = t & 63;
  const int quad = lid >> 4, l16 = lid & 15;

  const float*  frow  = feat + (size_t)b * kM;
  const int*    idxh  = sidx + h * kM;
  const __bf16* qin_b = qin + (size_t)b * kM;
  const __bf16* wq_h  = wq + h * 2048;
  const __bf16* wk_h  = wk + h * 2048;
  float* attn_out = out + (size_t)kB * kM + ((size_t)(b * kH + h)) * 4096;

  // ---- P1: gather kf[n][k] = feat[idx[h][n*64+k]] (global scattered, L1/L2-hot row)
#pragma unroll
  for (int j = 0; j < 16; ++j) {
    int i  = t + j * 256;
    int ix = idxh[i];
    s_kf[(i >> 6) * 72 + (i & 63)] = (__bf16)frow[ix];
  }

  // ---- P2: q-GEMM  q[n][e] = qin[n][k] * Wq_scaled[e][k]   (global-only inputs)
  v4f dq0 = {0.f, 0.f, 0.f, 0.f}, dq1 = {0.f, 0.f, 0.f, 0.f};
#pragma unroll
  for (int kt = 0; kt < 2; ++kt) {
    v8bf a  = *(const v8bf*)(qin_b + (16 * w + l16) * 64 + 32 * kt + 8 * quad);
    v8bf b0 = *(const v8bf*)(wq_h + l16 * 64 + 32 * kt + 8 * quad);
    v8bf b1 = *(const v8bf*)(wq_h + (16 + l16) * 64 + 32 * kt + 8 * quad);
    dq0 = __builtin_amdgcn_mfma_f32_16x16x32_bf16(a, b0, dq0, 0, 0, 0);
    dq1 = __builtin_amdgcn_mfma_f32_16x16x32_bf16(a, b1, dq1, 0, 0, 0);
  }
#pragma unroll
  for (int r = 0; r < 4; ++r) {
    s_q[(16 * w + 4 * quad + r) * 40 + l16]      = (__bf16)dq0[r];
    s_q[(16 * w + 4 * quad + r) * 40 + 16 + l16] = (__bf16)dq1[r];
  }

  __syncthreads();  // b1: s_kf visible

  // ---- P3: K-GEMM  K[n][d] = kf[n][k] * Wk[d][k]
  {
    v4f dk0 = {0.f, 0.f, 0.f, 0.f}, dk1 = {0.f, 0.f, 0.f, 0.f};
#pragma unroll
    for (int kt = 0; kt < 2; ++kt) {
      v8bf a  = *(const v8bf*)(s_kf + (16 * w + l16) * 72 + 32 * kt + 8 * quad);
      v8bf b0 = *(const v8bf*)(wk_h + l16 * 64 + 32 * kt + 8 * quad);
      v8bf b1 = *(const v8bf*)(wk_h + (16 + l16) * 64 + 32 * kt + 8 * quad);
      dk0 = __builtin_amdgcn_mfma_f32_16x16x32_bf16(a, b0, dk0, 0, 0, 0);
      dk1 = __builtin_amdgcn_mfma_f32_16x16x32_bf16(a, b1, dk1, 0, 0, 0);
    }
#pragma unroll
    for (int r = 0; r < 4; ++r) {
      s_K[(16 * w + 4 * quad + r) * 40 + l16]      = (__bf16)dk0[r];
      s_K[(16 * w + 4 * quad + r) * 40 + 16 + l16] = (__bf16)dk1[r];
    }
  }

  // ---- P4: windowed conv + relu + residual, written TRANSPOSED (v^T[s][n])
  {
    const int n = t & 63, p0 = (t >> 6) * 16;
    float w1[4][3], w2[4];
#pragma unroll
    for (int d = 0; d < 4; ++d) {
#pragma unroll
      for (int c = 0; c < 3; ++c) w1[d][c] = Wv1[(h * 4 + d) * 3 + c];
      w2[d] = Wv2[h * 4 + d];
    }
    float x[18];
#pragma unroll
    for (int c = 0; c < 18; ++c) {
      int col = p0 + c;
      x[c] = (col < 64) ? (float)s_kf[n * 72 + col] : 0.f;
    }
#pragma unroll
    for (int pp = 0; pp < 16; ++pp) {
      float acc = x[pp];
#pragma unroll
      for (int d = 0; d < 4; ++d) {
        float v1 = fmaf(x[pp + 2], w1[d][2], fmaf(x[pp + 1], w1[d][1], x[pp] * w1[d][0]));
        acc = fmaf(fmaxf(v1, 0.f), w2[d], acc);
      }
      s_vT[(p0 + pp) * 72 + n] = (__bf16)acc;  // conflict-free: wave writes one row
    }
  }

  __syncthreads();  // b2: s_q, s_K, s_vT visible

  // ---- P5: scores[qi][n] = q[qi][d] * K[n][d]   (K-dim = 32, single MFMA step)
  {
    v4f ds[4] = {{0.f, 0.f, 0.f, 0.f}, {0.f, 0.f, 0.f, 0.f},
                 {0.f, 0.f, 0.f, 0.f}, {0.f, 0.f, 0.f, 0.f}};
    v8bf a = *(const v8bf*)(s_q + (16 * w + l16) * 40 + 8 * quad);
#pragma unroll
    for (int nt = 0; nt < 4; ++nt) {
      v8bf bb = *(const v8bf*)(s_K + (16 * nt + l16) * 40 + 8 * quad);
      ds[nt] = __builtin_amdgcn_mfma_f32_16x16x32_bf16(a, bb, ds[nt], 0, 0, 0);
    }
#pragma unroll
    for (int nt = 0; nt < 4; ++nt)
#pragma unroll
      for (int r = 0; r < 4; ++r)
        s_sc[(16 * w + 4 * quad + r) * 72 + 16 * nt + l16] = (__bf16)ds[nt][r];
  }
  // no barrier: wave w owns rows 16w..16w+15 of s_sc end-to-end

  // ---- P6: softmax over n (4 rows per iteration, 16-lane groups), write attn out
#pragma unroll
  for (int rr = 0; rr < 4; ++rr) {
    const int row = 16 * w + 4 * rr + quad;
    v4bf pv = *(const v4bf*)(s_sc + row * 72 + 4 * l16);
    float e0 = (float)pv[0], e1 = (float)pv[1], e2 = (float)pv[2], e3 = (float)pv[3];
    float mx = fmaxf(fmaxf(e0, e1), fmaxf(e2, e3));
#pragma unroll
    for (int mk = 8; mk > 0; mk >>= 1) mx = fmaxf(mx, __shfl_xor(mx, mk));
    e0 = __expf(e0 - mx); e1 = __expf(e1 - mx);
    e2 = __expf(e2 - mx); e3 = __expf(e3 - mx);
    float ssum = e0 + e1 + e2 + e3;
#pragma unroll
    for (int mk = 8; mk > 0; mk >>= 1) ssum += __shfl_xor(ssum, mk);
    const float inv = 1.0f / ssum;
    e0 *= inv; e1 *= inv; e2 *= inv; e3 *= inv;
    *(float4*)(attn_out + row * 64 + 4 * l16) = make_float4(e0, e1, e2, e3);
    v4bf st;
    st[0] = (__bf16)e0; st[1] = (__bf16)e1; st[2] = (__bf16)e2; st[3] = (__bf16)e3;
    *(v4bf*)(s_sc + row * 72 + 4 * l16) = st;
  }

  // ---- P7: o[qi][s] = attn[qi][n] * vT[s][n]
  v4f dO[4] = {{0.f, 0.f, 0.f, 0.f}, {0.f, 0.f, 0.f, 0.f},
               {0.f, 0.f, 0.f, 0.f}, {0.f, 0.f, 0.f, 0.f}};
#pragma unroll
  for (int kt = 0; kt < 2; ++kt) {
    v8bf a = *(const v8bf*)(s_sc + (16 * w + l16) * 72 + 32 * kt + 8 * quad);
#pragma unroll
    for (int st = 0; st < 4; ++st) {
      v8bf bb = *(const v8bf*)(s_vT + (16 * st + l16) * 72 + 32 * kt + 8 * quad);
      dO[st] = __builtin_amdgcn_mfma_f32_16x16x32_bf16(a, bb, dO[st], 0, 0, 0);
    }
  }

  // ---- P8: store o bf16 directly to ws (L2 merges the 32B segments)
  __bf16* orow = o_ws + (size_t)(b * 64) * 512 + h * 64;
#pragma unroll
  for (int st = 0; st < 4; ++st)
#pragma unroll
    for (int r = 0; r < 4; ++r)
      orow[(size_t)(16 * w + 4 * quad + r) * 512 + 16 * st + l16] = (__bf16)dO[st][r];
}

// ---------------- K3: fc GEMM  out[bn][o] = o_ws[bn][f] * Wfc[o][f], f=512 ----------------
__global__ __launch_bounds__(256, 4) void k3_fc(
    const __bf16* __restrict__ o_ws, const __bf16* __restrict__ wfc,
    float* __restrict__ out) {
  const int t = threadIdx.x, w = t >> 6, lid = t & 63;
  const int quad = lid >> 4, l16 = lid & 15;
  const size_t row0 = (size_t)blockIdx.x * 64 + 16 * w;
  v4f d[4] = {{0.f, 0.f, 0.f, 0.f}, {0.f, 0.f, 0.f, 0.f},
              {0.f, 0.f, 0.f, 0.f}, {0.f, 0.f, 0.f, 0.f}};
#pragma unroll 4
  for (int kt = 0; kt < 16; ++kt) {
    v8bf a = *(const v8bf*)(o_ws + (row0 + l16) * 512 + 32 * kt + 8 * quad);
#pragma unroll
    for (int nt = 0; nt < 4; ++nt) {
      v8bf bb = *(const v8bf*)(wfc + (16 * nt + l16) * 512 + 32 * kt + 8 * quad);
      d[nt] = __builtin_amdgcn_mfma_f32_16x16x32_bf16(a, bb, d[nt], 0, 0, 0);
    }
  }
#pragma unroll
  for (int nt = 0; nt < 4; ++nt)
#pragma unroll
    for (int r = 0; r < 4; ++r)
      out[(row0 + 4 * quad + r) * 64 + 16 * nt + l16] = d[nt][r];
}

}  // namespace

extern "C" void kernel_launch(void* const* d_in, const int* in_sizes, int n_in,
                              void* d_out, int out_size, void* d_ws, size_t ws_size,
                              hipStream_t stream) {
  (void)in_sizes; (void)n_in; (void)out_size; (void)ws_size;
  const float* features = (const float*)d_in[0];
  const int*   sidx     = (const int*)d_in[1];
  const float* gamma    = (const float*)d_in[2];
  const float* beta     = (const float*)d_in[3];
  const float* Wq       = (const float*)d_in[4];
  const float* Wk       = (const float*)d_in[5];
  const float* Wv1      = (const float*)d_in[6];
  const float* Wv2      = (const float*)d_in[7];
  const float* Wfc      = (const float*)d_in[8];
  float* out = (float*)d_out;

  char* ws = (char*)d_ws;
  __bf16* ws_qin = (__bf16*)(ws + WS_QIN);
  __bf16* ws_o   = (__bf16*)(ws + WS_O);
  __bf16* ws_wq  = (__bf16*)(ws + WS_WQ);
  __bf16* ws_wk  = (__bf16*)(ws + WS_WK);
  __bf16* ws_wfc = (__bf16*)(ws + WS_WFC);

  hipLaunchKernelGGL(k0_weights, dim3(256), dim3(256), 0, stream,
                     Wq, Wk, Wfc, ws_wq, ws_wk, ws_wfc);
  hipLaunchKernelGGL(k1_ln, dim3(kB), dim3(256), 0, stream,
                     features, gamma, beta, ws_qin);
  hipLaunchKernelGGL(k2_attn, dim3(kH, kB), dim3(256), 0, stream,
                     features, sidx, ws_qin, ws_wq, ws_wk, Wv1, Wv2, ws_o, out);
  hipLaunchKernelGGL(k3_fc, dim3(kB), dim3(256), 0, stream,
                     ws_o, ws_wfc, out);
}

// Round 3
// 157.079 us; speedup vs baseline: 3.1744x; 1.0587x over previous
//
#include <hip/hip_runtime.h>

typedef __bf16 v8bf __attribute__((ext_vector_type(8)));
typedef __bf16 v4bf __attribute__((ext_vector_type(4)));
typedef float  v4f  __attribute__((ext_vector_type(4)));

namespace {

constexpr int kB = 512, kM = 4096, kH = 8;

// ws layout (bytes)
constexpr size_t WS_QIN = 0;                                   // 512*4096 bf16 = 4 MB (tile-swizzled)
constexpr size_t WS_O   = (size_t)4 << 20;                     // 32768*512 bf16 = 32 MB (tile-swizzled)
constexpr size_t WS_WQ  = WS_O + (size_t)32768 * 512 * 2;      // 16384 bf16 (B-tiles)
constexpr size_t WS_WK  = WS_WQ + 32768;                       // 16384 bf16 (B-tiles)
constexpr size_t WS_WFC = WS_WK + 32768;                       // 32768 bf16 (B-tiles)

// Tile swizzle: element (r, c) of a row-major [R x C] matrix lives at
//   tile = (r>>4)*(C/32) + (c>>5);  addr = tile*512 + (r&15)*32 + (c&31)
// so an MFMA 16x32 fragment (A or B) is one contiguous 1 KB block per wave.

// ---------------- K0: weight casts + swizzle (1/64 folded into Wq) ----------------
__global__ __launch_bounds__(256) void k0_weights(
    const float* __restrict__ Wq, const float* __restrict__ Wk,
    const float* __restrict__ Wfc,
    __bf16* __restrict__ wq, __bf16* __restrict__ wk, __bf16* __restrict__ wfc) {
  int i = blockIdx.x * 256 + threadIdx.x;
  if (i < 16384) {
    int e = i >> 6, k = i & 63;
    int dst = ((e >> 4) * 2 + (k >> 5)) * 512 + (e & 15) * 32 + (k & 31);
    wq[dst] = (__bf16)(Wq[i] * 0.015625f);
  } else if (i < 32768) {
    int j = i - 16384;
    int e = j >> 6, k = j & 63;
    int dst = ((e >> 4) * 2 + (k >> 5)) * 512 + (e & 15) * 32 + (k & 31);
    wk[dst] = (__bf16)Wk[j];
  } else {
    int j = i - 32768;
    int o = j >> 9, f = j & 511;
    int dst = ((o >> 4) * 16 + (f >> 5)) * 512 + (o & 15) * 32 + (f & 31);
    wfc[dst] = (__bf16)Wfc[j];
  }
}

// ---------------- K1: LayerNorm -> bf16 qin (tile-swizzled) ----------------
__global__ __launch_bounds__(256) void k1_ln(
    const float* __restrict__ feat, const float* __restrict__ gamma,
    const float* __restrict__ beta, __bf16* __restrict__ qin) {
  __shared__ float red[4];
  const int b = blockIdx.x, t = threadIdx.x, lane = t & 63, wv = t >> 6;
  const float* frow = feat + (size_t)b * kM;
  float xs[16];
  float s = 0.f;
#pragma unroll
  for (int j = 0; j < 16; ++j) { float x = frow[t + j * 256]; xs[j] = x; s += x; }
#pragma unroll
  for (int o = 32; o > 0; o >>= 1) s += __shfl_xor(s, o);
  if (lane == 0) red[wv] = s;
  __syncthreads();
  const float mu = (red[0] + red[1] + red[2] + red[3]) * (1.f / kM);
  float v = 0.f;
#pragma unroll
  for (int j = 0; j < 16; ++j) { float d = xs[j] - mu; v += d * d; }
#pragma unroll
  for (int o = 32; o > 0; o >>= 1) v += __shfl_xor(v, o);
  __syncthreads();
  if (lane == 0) red[wv] = v;
  __syncthreads();
  const float var  = (red[0] + red[1] + red[2] + red[3]) * (1.f / kM);
  const float rstd = rsqrtf(var + 1e-5f);
#pragma unroll
  for (int j = 0; j < 16; ++j) {
    int m = t + j * 256;
    int n = m >> 6, k = m & 63;
    int dst = ((n >> 4) * 2 + (k >> 5)) * 512 + (n & 15) * 32 + (k & 31);
    qin[(size_t)b * kM + dst] = (__bf16)((xs[j] - mu) * rstd * gamma[m] + beta[m]);
  }
}

// ---------------- K2: per-(b,h) attention core ----------------
// LDS 28,672 B (s_sc aliases s_kf) -> 5 blocks/CU.
__global__ __launch_bounds__(256, 5) void k2_attn(
    const float* __restrict__ feat, const int* __restrict__ sidx,
    const __bf16* __restrict__ qin, const __bf16* __restrict__ wq,
    const __bf16* __restrict__ wk, const float* __restrict__ Wv1,
    const float* __restrict__ Wv2, __bf16* __restrict__ o_ws,
    float* __restrict__ out) {
  __shared__ __align__(16) __bf16 smem[14336];  // 28,672 B
  __bf16* s_kf = smem;          // 64 x 72  (kf; later aliased as scores/attn)
  __bf16* s_q  = smem + 4608;   // 64 x 40
  __bf16* s_K  = smem + 7168;   // 64 x 40
  __bf16* s_vT = smem + 9728;   // 64 x 72  (v^T [s][n])
  __bf16* s_sc = smem;          // ALIAS of s_kf (dead after barrier 2)

  const int b = blockIdx.x, h = blockIdx.y;   // b-major: 8 heads of b land on one XCD (%8)
  const int t = threadIdx.x, w = t >> 6, lid = t & 63;
  const int quad = lid >> 4, l16 = lid & 15;

  const float*  frow  = feat + (size_t)b * kM;
  const int*    idxh  = sidx + h * kM;
  const __bf16* qin_b = qin + (size_t)b * kM;
  float* attn_out = out + (size_t)kB * kM + ((size_t)(b * kH + h)) * 4096;

  // ---- P1: gather kf[n][k] = feat[idx[h][n*64+k]]
#pragma unroll
  for (int j = 0; j < 16; ++j) {
    int i  = t + j * 256;
    int ix = idxh[i];
    s_kf[(i >> 6) * 72 + (i & 63)] = (__bf16)frow[ix];
  }

  // ---- P2: q-GEMM (global swizzled inputs, fully coalesced)
  v4f dq0 = {0.f, 0.f, 0.f, 0.f}, dq1 = {0.f, 0.f, 0.f, 0.f};
#pragma unroll
  for (int kt = 0; kt < 2; ++kt) {
    v8bf a  = *(const v8bf*)(qin_b + (2 * w + kt) * 512 + l16 * 32 + 8 * quad);
    v8bf b0 = *(const v8bf*)(wq + (size_t)(4 * h + kt) * 512 + l16 * 32 + 8 * quad);
    v8bf b1 = *(const v8bf*)(wq + (size_t)(4 * h + 2 + kt) * 512 + l16 * 32 + 8 * quad);
    dq0 = __builtin_amdgcn_mfma_f32_16x16x32_bf16(a, b0, dq0, 0, 0, 0);
    dq1 = __builtin_amdgcn_mfma_f32_16x16x32_bf16(a, b1, dq1, 0, 0, 0);
  }
#pragma unroll
  for (int r = 0; r < 4; ++r) {
    s_q[(16 * w + 4 * quad + r) * 40 + l16]      = (__bf16)dq0[r];
    s_q[(16 * w + 4 * quad + r) * 40 + 16 + l16] = (__bf16)dq1[r];
  }

  __syncthreads();  // b1: s_kf visible

  // ---- P3: K-GEMM
  {
    v4f dk0 = {0.f, 0.f, 0.f, 0.f}, dk1 = {0.f, 0.f, 0.f, 0.f};
#pragma unroll
    for (int kt = 0; kt < 2; ++kt) {
      v8bf a  = *(const v8bf*)(s_kf + (16 * w + l16) * 72 + 32 * kt + 8 * quad);
      v8bf b0 = *(const v8bf*)(wk + (size_t)(4 * h + kt) * 512 + l16 * 32 + 8 * quad);
      v8bf b1 = *(const v8bf*)(wk + (size_t)(4 * h + 2 + kt) * 512 + l16 * 32 + 8 * quad);
      dk0 = __builtin_amdgcn_mfma_f32_16x16x32_bf16(a, b0, dk0, 0, 0, 0);
      dk1 = __builtin_amdgcn_mfma_f32_16x16x32_bf16(a, b1, dk1, 0, 0, 0);
    }
#pragma unroll
    for (int r = 0; r < 4; ++r) {
      s_K[(16 * w + 4 * quad + r) * 40 + l16]      = (__bf16)dk0[r];
      s_K[(16 * w + 4 * quad + r) * 40 + 16 + l16] = (__bf16)dk1[r];
    }
  }

  // ---- P4: windowed conv + relu + residual, written transposed (v^T[s][n])
  {
    const int n = t & 63, p0 = (t >> 6) * 16;
    float w1[4][3], w2[4];
#pragma unroll
    for (int d = 0; d < 4; ++d) {
#pragma unroll
      for (int c = 0; c < 3; ++c) w1[d][c] = Wv1[(h * 4 + d) * 3 + c];
      w2[d] = Wv2[h * 4 + d];
    }
    float x[18];
#pragma unroll
    for (int c = 0; c < 18; ++c) {
      int col = p0 + c;
      x[c] = (col < 64) ? (float)s_kf[n * 72 + col] : 0.f;
    }
#pragma unroll
    for (int pp = 0; pp < 16; ++pp) {
      float acc = x[pp];
#pragma unroll
      for (int d = 0; d < 4; ++d) {
        float v1 = fmaf(x[pp + 2], w1[d][2], fmaf(x[pp + 1], w1[d][1], x[pp] * w1[d][0]));
        acc = fmaf(fmaxf(v1, 0.f), w2[d], acc);
      }
      s_vT[(p0 + pp) * 72 + n] = (__bf16)acc;
    }
  }

  __syncthreads();  // b2: s_q, s_K, s_vT visible; s_kf dead (becomes s_sc)

  // ---- P5: scores[qi][n] = q[qi][d] * K[n][d]
  {
    v4f ds[4] = {{0.f, 0.f, 0.f, 0.f}, {0.f, 0.f, 0.f, 0.f},
                 {0.f, 0.f, 0.f, 0.f}, {0.f, 0.f, 0.f, 0.f}};
    v8bf a = *(const v8bf*)(s_q + (16 * w + l16) * 40 + 8 * quad);
#pragma unroll
    for (int nt = 0; nt < 4; ++nt) {
      v8bf bb = *(const v8bf*)(s_K + (16 * nt + l16) * 40 + 8 * quad);
      ds[nt] = __builtin_amdgcn_mfma_f32_16x16x32_bf16(a, bb, ds[nt], 0, 0, 0);
    }
#pragma unroll
    for (int nt = 0; nt < 4; ++nt)
#pragma unroll
      for (int r = 0; r < 4; ++r)
        s_sc[(16 * w + 4 * quad + r) * 72 + 16 * nt + l16] = (__bf16)ds[nt][r];
  }
  // no barrier: wave w owns rows 16w..16w+15 of s_sc end-to-end

  // ---- P6: softmax + attn output
#pragma unroll
  for (int rr = 0; rr < 4; ++rr) {
    const int row = 16 * w + 4 * rr + quad;
    v4bf pv = *(const v4bf*)(s_sc + row * 72 + 4 * l16);
    float e0 = (float)pv[0], e1 = (float)pv[1], e2 = (float)pv[2], e3 = (float)pv[3];
    float mx = fmaxf(fmaxf(e0, e1), fmaxf(e2, e3));
#pragma unroll
    for (int mk = 8; mk > 0; mk >>= 1) mx = fmaxf(mx, __shfl_xor(mx, mk));
    e0 = __expf(e0 - mx); e1 = __expf(e1 - mx);
    e2 = __expf(e2 - mx); e3 = __expf(e3 - mx);
    float ssum = e0 + e1 + e2 + e3;
#pragma unroll
    for (int mk = 8; mk > 0; mk >>= 1) ssum += __shfl_xor(ssum, mk);
    const float inv = 1.0f / ssum;
    e0 *= inv; e1 *= inv; e2 *= inv; e3 *= inv;
    *(float4*)(attn_out + row * 64 + 4 * l16) = make_float4(e0, e1, e2, e3);
    v4bf st;
    st[0] = (__bf16)e0; st[1] = (__bf16)e1; st[2] = (__bf16)e2; st[3] = (__bf16)e3;
    *(v4bf*)(s_sc + row * 72 + 4 * l16) = st;
  }

  // ---- P7: o[qi][s] = attn[qi][n] * vT[s][n]
  v4f dO[4] = {{0.f, 0.f, 0.f, 0.f}, {0.f, 0.f, 0.f, 0.f},
               {0.f, 0.f, 0.f, 0.f}, {0.f, 0.f, 0.f, 0.f}};
#pragma unroll
  for (int kt = 0; kt < 2; ++kt) {
    v8bf a = *(const v8bf*)(s_sc + (16 * w + l16) * 72 + 32 * kt + 8 * quad);
#pragma unroll
    for (int st = 0; st < 4; ++st) {
      v8bf bb = *(const v8bf*)(s_vT + (16 * st + l16) * 72 + 32 * kt + 8 * quad);
      dO[st] = __builtin_amdgcn_mfma_f32_16x16x32_bf16(a, bb, dO[st], 0, 0, 0);
    }
  }

  // ---- P8: store o to ws in A-fragment tile order
  // global row = b*64 + 16w + 4q + r  ->  row tile b*4+w ; f = h*64 + 16st + l16
  __bf16* obase = o_ws + ((size_t)(b * 4 + w) * 16 + h * 2) * 512;
#pragma unroll
  for (int st = 0; st < 4; ++st)
#pragma unroll
    for (int r = 0; r < 4; ++r)
      obase[(st >> 1) * 512 + (4 * quad + r) * 32 + (st & 1) * 16 + l16] = (__bf16)dO[st][r];
}

// ---------------- K3: fc GEMM, fully coalesced tile loads ----------------
__global__ __launch_bounds__(256, 4) void k3_fc(
    const __bf16* __restrict__ o_ws, const __bf16* __restrict__ wfc,
    float* __restrict__ out) {
  const int t = threadIdx.x, w = t >> 6, lid = t & 63;
  const int quad = lid >> 4, l16 = lid & 15;
  const size_t row0 = (size_t)blockIdx.x * 64 + 16 * w;
  const __bf16* abase = o_ws + (size_t)(blockIdx.x * 4 + w) * 16 * 512;
  v4f d[4] = {{0.f, 0.f, 0.f, 0.f}, {0.f, 0.f, 0.f, 0.f},
              {0.f, 0.f, 0.f, 0.f}, {0.f, 0.f, 0.f, 0.f}};
#pragma unroll 4
  for (int kt = 0; kt < 16; ++kt) {
    v8bf a = *(const v8bf*)(abase + kt * 512 + l16 * 32 + 8 * quad);
#pragma unroll
    for (int nt = 0; nt < 4; ++nt) {
      v8bf bb = *(const v8bf*)(wfc + (size_t)(nt * 16 + kt) * 512 + l16 * 32 + 8 * quad);
      d[nt] = __builtin_amdgcn_mfma_f32_16x16x32_bf16(a, bb, d[nt], 0, 0, 0);
    }
  }
#pragma unroll
  for (int nt = 0; nt < 4; ++nt)
#pragma unroll
    for (int r = 0; r < 4; ++r)
      out[(row0 + 4 * quad + r) * 64 + 16 * nt + l16] = d[nt][r];
}

}  // namespace

extern "C" void kernel_launch(void* const* d_in, const int* in_sizes, int n_in,
                              void* d_out, int out_size, void* d_ws, size_t ws_size,
                              hipStream_t stream) {
  (void)in_sizes; (void)n_in; (void)out_size; (void)ws_size;
  const float* features = (const float*)d_in[0];
  const int*   sidx     = (const int*)d_in[1];
  const float* gamma    = (const float*)d_in[2];
  const float* beta     = (const float*)d_in[3];
  const float* Wq       = (const float*)d_in[4];
  const float* Wk       = (const float*)d_in[5];
  const float* Wv1      = (const float*)d_in[6];
  const float* Wv2      = (const float*)d_in[7];
  const float* Wfc      = (const float*)d_in[8];
  float* out = (float*)d_out;

  char* ws = (char*)d_ws;
  __bf16* ws_qin = (__bf16*)(ws + WS_QIN);
  __bf16* ws_o   = (__bf16*)(ws + WS_O);
  __bf16* ws_wq  = (__bf16*)(ws + WS_WQ);
  __bf16* ws_wk  = (__bf16*)(ws + WS_WK);
  __bf16* ws_wfc = (__bf16*)(ws + WS_WFC);

  hipLaunchKernelGGL(k0_weights, dim3(256), dim3(256), 0, stream,
                     Wq, Wk, Wfc, ws_wq, ws_wk, ws_wfc);
  hipLaunchKernelGGL(k1_ln, dim3(kB), dim3(256), 0, stream,
                     features, gamma, beta, ws_qin);
  hipLaunchKernelGGL(k2_attn, dim3(kB, kH), dim3(256), 0, stream,
                     features, sidx, ws_qin, ws_wq, ws_wk, Wv1, Wv2, ws_o, out);
  hipLaunchKernelGGL(k3_fc, dim3(kB), dim3(256), 0, stream,
                     ws_o, ws_wfc, out);
}

// Round 4
// 150.210 us; speedup vs baseline: 3.3195x; 1.0457x over previous
//
#include <hip/hip_runtime.h>

typedef __bf16 v8bf __attribute__((ext_vector_type(8)));
typedef __bf16 v4bf __attribute__((ext_vector_type(4)));
typedef __bf16 v2bf __attribute__((ext_vector_type(2)));
typedef float  v4f  __attribute__((ext_vector_type(4)));

namespace {

constexpr int kB = 512, kM = 4096, kH = 8;

// ws layout (bytes)
constexpr size_t WS_QIN = 0;                                   // 512*4096 bf16 = 4 MB (tile-swizzled)
constexpr size_t WS_O   = (size_t)4 << 20;                     // 32768*512 bf16 = 32 MB (tile-swizzled)
constexpr size_t WS_WQ  = WS_O + (size_t)32768 * 512 * 2;      // 16384 bf16 (B-tiles)
constexpr size_t WS_WK  = WS_WQ + 32768;                       // 16384 bf16 (B-tiles)
constexpr size_t WS_WFC = WS_WK + 32768;                       // 32768 bf16 (B-tiles)

// Tile swizzle: element (r, c) of a row-major [R x C] matrix lives at
//   tile = (r>>4)*(C/32) + (c>>5);  addr = tile*512 + (r&15)*32 + (c&31)

// ---------------- K0: weight casts + swizzle (1/64 folded into Wq) ----------------
__global__ __launch_bounds__(256) void k0_weights(
    const float* __restrict__ Wq, const float* __restrict__ Wk,
    const float* __restrict__ Wfc,
    __bf16* __restrict__ wq, __bf16* __restrict__ wk, __bf16* __restrict__ wfc) {
  int i = blockIdx.x * 256 + threadIdx.x;
  if (i < 16384) {
    int e = i >> 6, k = i & 63;
    int dst = ((e >> 4) * 2 + (k >> 5)) * 512 + (e & 15) * 32 + (k & 31);
    wq[dst] = (__bf16)(Wq[i] * 0.015625f);
  } else if (i < 32768) {
    int j = i - 16384;
    int e = j >> 6, k = j & 63;
    int dst = ((e >> 4) * 2 + (k >> 5)) * 512 + (e & 15) * 32 + (k & 31);
    wk[dst] = (__bf16)Wk[j];
  } else {
    int j = i - 32768;
    int o = j >> 9, f = j & 511;
    int dst = ((o >> 4) * 16 + (f >> 5)) * 512 + (o & 15) * 32 + (f & 31);
    wfc[dst] = (__bf16)Wfc[j];
  }
}

// ---------------- K1: LayerNorm -> bf16 qin (tile-swizzled) ----------------
__global__ __launch_bounds__(256) void k1_ln(
    const float* __restrict__ feat, const float* __restrict__ gamma,
    const float* __restrict__ beta, __bf16* __restrict__ qin) {
  __shared__ float red[4];
  const int b = blockIdx.x, t = threadIdx.x, lane = t & 63, wv = t >> 6;
  const float* frow = feat + (size_t)b * kM;
  float xs[16];
  float s = 0.f;
#pragma unroll
  for (int j = 0; j < 16; ++j) { float x = frow[t + j * 256]; xs[j] = x; s += x; }
#pragma unroll
  for (int o = 32; o > 0; o >>= 1) s += __shfl_xor(s, o);
  if (lane == 0) red[wv] = s;
  __syncthreads();
  const float mu = (red[0] + red[1] + red[2] + red[3]) * (1.f / kM);
  float v = 0.f;
#pragma unroll
  for (int j = 0; j < 16; ++j) { float d = xs[j] - mu; v += d * d; }
#pragma unroll
  for (int o = 32; o > 0; o >>= 1) v += __shfl_xor(v, o);
  __syncthreads();
  if (lane == 0) red[wv] = v;
  __syncthreads();
  const float var  = (red[0] + red[1] + red[2] + red[3]) * (1.f / kM);
  const float rstd = rsqrtf(var + 1e-5f);
#pragma unroll
  for (int j = 0; j < 16; ++j) {
    int m = t + j * 256;
    int n = m >> 6, k = m & 63;
    int dst = ((n >> 4) * 2 + (k >> 5)) * 512 + (n & 15) * 32 + (k & 31);
    qin[(size_t)b * kM + dst] = (__bf16)((xs[j] - mu) * rstd * gamma[m] + beta[m]);
  }
}

// ---------------- K2: per-(b,h) attention core ----------------
// LDS 36,864 B -> 4 blocks/CU. Gather is LDS->LDS (feat staged bf16), not via L1.
__global__ __launch_bounds__(256, 4) void k2_attn(
    const float* __restrict__ feat, const int* __restrict__ sidx,
    const __bf16* __restrict__ qin, const __bf16* __restrict__ wq,
    const __bf16* __restrict__ wk, const float* __restrict__ Wv1,
    const float* __restrict__ Wv2, __bf16* __restrict__ o_ws,
    float* __restrict__ out) {
  __shared__ __align__(16) __bf16 smem[18432];  // 36,864 B
  __bf16* s_feat = smem;          // 4096    (bf16 feature row; dead after gather)
  __bf16* s_kf   = smem + 4096;   // 64 x 72 (kf; later aliased as scores/attn)
  __bf16* s_q    = smem + 8704;   // 64 x 40
  __bf16* s_K    = smem + 11264;  // 64 x 40
  __bf16* s_vT   = smem + 13824;  // 64 x 72 (v^T [s][n])
  __bf16* s_sc   = smem + 4096;   // ALIAS of s_kf (dead after barrier C)

  const int b = blockIdx.x, h = blockIdx.y;   // heads of one b: linear ids 512 apart -> same XCD
  const int t = threadIdx.x, w = t >> 6, lid = t & 63;
  const int quad = lid >> 4, l16 = lid & 15;

  const float*  frow  = feat + (size_t)b * kM;
  const int*    idxh  = sidx + h * kM;
  const __bf16* qin_b = qin + (size_t)b * kM;
  float* attn_out = out + (size_t)kB * kM + ((size_t)(b * kH + h)) * 4096;

  // ---- P0a: prefetch gather indices (coalesced global, overlaps with staging)
  int idxr[16];
#pragma unroll
  for (int j = 0; j < 16; ++j) idxr[j] = idxh[t + j * 256];

  // ---- P0b: stage feature row as bf16 into LDS (coalesced float4 loads)
  {
    const float4* frow4 = reinterpret_cast<const float4*>(frow);
#pragma unroll
    for (int j = 0; j < 4; ++j) {
      int i4 = t + j * 256;
      float4 f = frow4[i4];
      v4bf o4;
      o4[0] = (__bf16)f.x; o4[1] = (__bf16)f.y; o4[2] = (__bf16)f.z; o4[3] = (__bf16)f.w;
      *(v4bf*)(s_feat + 4 * i4) = o4;
    }
  }

  // ---- P0c: zero s_kf pad columns 64..71 (so conv tail reads are branch-free)
  if (t < 64) {
    v8bf z = {};
    *(v8bf*)(s_kf + t * 72 + 64) = z;
  }

  // ---- P0d: q-GEMM (global swizzled inputs only, no LDS deps)
  v4f dq0 = {0.f, 0.f, 0.f, 0.f}, dq1 = {0.f, 0.f, 0.f, 0.f};
#pragma unroll
  for (int kt = 0; kt < 2; ++kt) {
    v8bf a  = *(const v8bf*)(qin_b + (2 * w + kt) * 512 + l16 * 32 + 8 * quad);
    v8bf b0 = *(const v8bf*)(wq + (size_t)(4 * h + kt) * 512 + l16 * 32 + 8 * quad);
    v8bf b1 = *(const v8bf*)(wq + (size_t)(4 * h + 2 + kt) * 512 + l16 * 32 + 8 * quad);
    dq0 = __builtin_amdgcn_mfma_f32_16x16x32_bf16(a, b0, dq0, 0, 0, 0);
    dq1 = __builtin_amdgcn_mfma_f32_16x16x32_bf16(a, b1, dq1, 0, 0, 0);
  }
#pragma unroll
  for (int r = 0; r < 4; ++r) {
    s_q[(16 * w + 4 * quad + r) * 40 + l16]      = (__bf16)dq0[r];
    s_q[(16 * w + 4 * quad + r) * 40 + 16 + l16] = (__bf16)dq1[r];
  }

  __syncthreads();  // barrier A: s_feat staged

  // ---- P1: gather kf from LDS (random b16 reads on the crossbar, not L1)
#pragma unroll
  for (int j = 0; j < 16; ++j) {
    int i = t + j * 256;
    s_kf[(i >> 6) * 72 + (i & 63)] = s_feat[idxr[j]];
  }

  __syncthreads();  // barrier B: s_kf ready

  // ---- P3: K-GEMM
  {
    v4f dk0 = {0.f, 0.f, 0.f, 0.f}, dk1 = {0.f, 0.f, 0.f, 0.f};
#pragma unroll
    for (int kt = 0; kt < 2; ++kt) {
      v8bf a  = *(const v8bf*)(s_kf + (16 * w + l16) * 72 + 32 * kt + 8 * quad);
      v8bf b0 = *(const v8bf*)(wk + (size_t)(4 * h + kt) * 512 + l16 * 32 + 8 * quad);
      v8bf b1 = *(const v8bf*)(wk + (size_t)(4 * h + 2 + kt) * 512 + l16 * 32 + 8 * quad);
      dk0 = __builtin_amdgcn_mfma_f32_16x16x32_bf16(a, b0, dk0, 0, 0, 0);
      dk1 = __builtin_amdgcn_mfma_f32_16x16x32_bf16(a, b1, dk1, 0, 0, 0);
    }
#pragma unroll
    for (int r = 0; r < 4; ++r) {
      s_K[(16 * w + 4 * quad + r) * 40 + l16]      = (__bf16)dk0[r];
      s_K[(16 * w + 4 * quad + r) * 40 + 16 + l16] = (__bf16)dk1[r];
    }
  }

  // ---- P4: windowed conv + relu + residual, written transposed (v^T[s][n])
  {
    const int n = t & 63, p0 = (t >> 6) * 16;
    float w1[4][3], w2[4];
#pragma unroll
    for (int d = 0; d < 4; ++d) {
#pragma unroll
      for (int c = 0; c < 3; ++c) w1[d][c] = Wv1[(h * 4 + d) * 3 + c];
      w2[d] = Wv2[h * 4 + d];
    }
    v8bf xa = *(const v8bf*)(s_kf + n * 72 + p0);
    v8bf xb = *(const v8bf*)(s_kf + n * 72 + p0 + 8);
    v2bf xc = *(const v2bf*)(s_kf + n * 72 + p0 + 16);  // pad cols are zeroed
    float x[18];
#pragma unroll
    for (int c = 0; c < 8; ++c) { x[c] = (float)xa[c]; x[c + 8] = (float)xb[c]; }
    x[16] = (float)xc[0]; x[17] = (float)xc[1];
#pragma unroll
    for (int pp = 0; pp < 16; ++pp) {
      float acc = x[pp];
#pragma unroll
      for (int d = 0; d < 4; ++d) {
        float v1 = fmaf(x[pp + 2], w1[d][2], fmaf(x[pp + 1], w1[d][1], x[pp] * w1[d][0]));
        acc = fmaf(fmaxf(v1, 0.f), w2[d], acc);
      }
      s_vT[(p0 + pp) * 72 + n] = (__bf16)acc;
    }
  }

  __syncthreads();  // barrier C: s_q, s_K, s_vT ready; s_kf dead (becomes s_sc)

  // ---- P5: scores[qi][n] = q[qi][d] * K[n][d]
  {
    v4f ds[4] = {{0.f, 0.f, 0.f, 0.f}, {0.f, 0.f, 0.f, 0.f},
                 {0.f, 0.f, 0.f, 0.f}, {0.f, 0.f, 0.f, 0.f}};
    v8bf a = *(const v8bf*)(s_q + (16 * w + l16) * 40 + 8 * quad);
#pragma unroll
    for (int nt = 0; nt < 4; ++nt) {
      v8bf bb = *(const v8bf*)(s_K + (16 * nt + l16) * 40 + 8 * quad);
      ds[nt] = __builtin_amdgcn_mfma_f32_16x16x32_bf16(a, bb, ds[nt], 0, 0, 0);
    }
#pragma unroll
    for (int nt = 0; nt < 4; ++nt)
#pragma unroll
      for (int r = 0; r < 4; ++r)
        s_sc[(16 * w + 4 * quad + r) * 72 + 16 * nt + l16] = (__bf16)ds[nt][r];
  }
  // no barrier: wave w owns rows 16w..16w+15 of s_sc end-to-end

  // ---- P6: softmax + attn output
#pragma unroll
  for (int rr = 0; rr < 4; ++rr) {
    const int row = 16 * w + 4 * rr + quad;
    v4bf pv = *(const v4bf*)(s_sc + row * 72 + 4 * l16);
    float e0 = (float)pv[0], e1 = (float)pv[1], e2 = (float)pv[2], e3 = (float)pv[3];
    float mx = fmaxf(fmaxf(e0, e1), fmaxf(e2, e3));
#pragma unroll
    for (int mk = 8; mk > 0; mk >>= 1) mx = fmaxf(mx, __shfl_xor(mx, mk));
    e0 = __expf(e0 - mx); e1 = __expf(e1 - mx);
    e2 = __expf(e2 - mx); e3 = __expf(e3 - mx);
    float ssum = e0 + e1 + e2 + e3;
#pragma unroll
    for (int mk = 8; mk > 0; mk >>= 1) ssum += __shfl_xor(ssum, mk);
    const float inv = 1.0f / ssum;
    e0 *= inv; e1 *= inv; e2 *= inv; e3 *= inv;
    *(float4*)(attn_out + row * 64 + 4 * l16) = make_float4(e0, e1, e2, e3);
    v4bf st;
    st[0] = (__bf16)e0; st[1] = (__bf16)e1; st[2] = (__bf16)e2; st[3] = (__bf16)e3;
    *(v4bf*)(s_sc + row * 72 + 4 * l16) = st;
  }

  // ---- P7: o[qi][s] = attn[qi][n] * vT[s][n]
  v4f dO[4] = {{0.f, 0.f, 0.f, 0.f}, {0.f, 0.f, 0.f, 0.f},
               {0.f, 0.f, 0.f, 0.f}, {0.f, 0.f, 0.f, 0.f}};
#pragma unroll
  for (int kt = 0; kt < 2; ++kt) {
    v8bf a = *(const v8bf*)(s_sc + (16 * w + l16) * 72 + 32 * kt + 8 * quad);
#pragma unroll
    for (int st = 0; st < 4; ++st) {
      v8bf bb = *(const v8bf*)(s_vT + (16 * st + l16) * 72 + 32 * kt + 8 * quad);
      dO[st] = __builtin_amdgcn_mfma_f32_16x16x32_bf16(a, bb, dO[st], 0, 0, 0);
    }
  }

  // ---- P8: store o to ws in A-fragment tile order
  __bf16* obase = o_ws + ((size_t)(b * 4 + w) * 16 + h * 2) * 512;
#pragma unroll
  for (int st = 0; st < 4; ++st)
#pragma unroll
    for (int r = 0; r < 4; ++r)
      obase[(st >> 1) * 512 + (4 * quad + r) * 32 + (st & 1) * 16 + l16] = (__bf16)dO[st][r];
}

// ---------------- K3: fc GEMM, fully coalesced tile loads ----------------
__global__ __launch_bounds__(256, 4) void k3_fc(
    const __bf16* __restrict__ o_ws, const __bf16* __restrict__ wfc,
    float* __restrict__ out) {
  const int t = threadIdx.x, w = t >> 6, lid = t & 63;
  const int quad = lid >> 4, l16 = lid & 15;
  const size_t row0 = (size_t)blockIdx.x * 64 + 16 * w;
  const __bf16* abase = o_ws + (size_t)(blockIdx.x * 4 + w) * 16 * 512;
  v4f d[4] = {{0.f, 0.f, 0.f, 0.f}, {0.f, 0.f, 0.f, 0.f},
              {0.f, 0.f, 0.f, 0.f}, {0.f, 0.f, 0.f, 0.f}};
#pragma unroll 4
  for (int kt = 0; kt < 16; ++kt) {
    v8bf a = *(const v8bf*)(abase + kt * 512 + l16 * 32 + 8 * quad);
#pragma unroll
    for (int nt = 0; nt < 4; ++nt) {
      v8bf bb = *(const v8bf*)(wfc + (size_t)(nt * 16 + kt) * 512 + l16 * 32 + 8 * quad);
      d[nt] = __builtin_amdgcn_mfma_f32_16x16x32_bf16(a, bb, d[nt], 0, 0, 0);
    }
  }
#pragma unroll
  for (int nt = 0; nt < 4; ++nt)
#pragma unroll
    for (int r = 0; r < 4; ++r)
      out[(row0 + 4 * quad + r) * 64 + 16 * nt + l16] = d[nt][r];
}

}  // namespace

extern "C" void kernel_launch(void* const* d_in, const int* in_sizes, int n_in,
                              void* d_out, int out_size, void* d_ws, size_t ws_size,
                              hipStream_t stream) {
  (void)in_sizes; (void)n_in; (void)out_size; (void)ws_size;
  const float* features = (const float*)d_in[0];
  const int*   sidx     = (const int*)d_in[1];
  const float* gamma    = (const float*)d_in[2];
  const float* beta     = (const float*)d_in[3];
  const float* Wq       = (const float*)d_in[4];
  const float* Wk       = (const float*)d_in[5];
  const float* Wv1      = (const float*)d_in[6];
  const float* Wv2      = (const float*)d_in[7];
  const float* Wfc      = (const float*)d_in[8];
  float* out = (float*)d_out;

  char* ws = (char*)d_ws;
  __bf16* ws_qin = (__bf16*)(ws + WS_QIN);
  __bf16* ws_o   = (__bf16*)(ws + WS_O);
  __bf16* ws_wq  = (__bf16*)(ws + WS_WQ);
  __bf16* ws_wk  = (__bf16*)(ws + WS_WK);
  __bf16* ws_wfc = (__bf16*)(ws + WS_WFC);

  hipLaunchKernelGGL(k0_weights, dim3(256), dim3(256), 0, stream,
                     Wq, Wk, Wfc, ws_wq, ws_wk, ws_wfc);
  hipLaunchKernelGGL(k1_ln, dim3(kB), dim3(256), 0, stream,
                     features, gamma, beta, ws_qin);
  hipLaunchKernelGGL(k2_attn, dim3(kB, kH), dim3(256), 0, stream,
                     features, sidx, ws_qin, ws_wq, ws_wk, Wv1, Wv2, ws_o, out);
  hipLaunchKernelGGL(k3_fc, dim3(kB), dim3(256), 0, stream,
                     ws_o, ws_wfc, out);
}